// Round 10
// baseline (141.563 us; speedup 1.0000x reference)
//
#include <hip/hip_runtime.h>
#include <hip/hip_bf16.h>

#define B_    16
#define N_    4
#define COUT  256
#define CIN   256
#define H_    64
#define W_    64
#define K_TOT (CIN * 9)    // 2304, k = p*256 + cin (p-major)
#define HW    (H_ * W_)    // 4096
#define NKT   (K_TOT / 64) // 36 K-tiles of 64
#define PAD   66
#define PLANE (PAD * PAD)  // 4356 padded pixels per (b, cb4) plane

typedef __attribute__((ext_vector_type(8))) short short8;
typedef __attribute__((ext_vector_type(4))) float f32x4;
typedef unsigned short ushort_t;

static __device__ __forceinline__ ushort_t f2bf(float f) {
    __hip_bfloat16 h = __float2bfloat16(f);
    return *reinterpret_cast<ushort_t*>(&h);
}

typedef __attribute__((address_space(3))) unsigned int lds_u32;
typedef __attribute__((address_space(1))) const unsigned int glb_u32;
static __device__ __forceinline__ void gl_lds16(const ushort_t* g, ushort_t* l) {
    __builtin_amdgcn_global_load_lds((glb_u32*)g, (lds_u32*)l, 16, 0, 0);
}

#define BARRIER() asm volatile("s_barrier" ::: "memory")
#define VMCNTN(N) asm volatile("s_waitcnt vmcnt(" #N ")" ::: "memory")

// ---------------------------------------------------------------------------
// Kernel 1: 9x9 rotation matrices, scaled by alpha.  rm[b*N_+n][9][9] floats.
// ---------------------------------------------------------------------------
__global__ void rot_mats_kernel(const float* __restrict__ alphas,
                                const float* __restrict__ angles,
                                float* __restrict__ rm) {
    int i = threadIdx.x;
    if (i >= B_ * N_) return;
    float th = angles[i], al = alphas[i];
    float xc = cosf(th), ys = sinf(th);
    float a = xc - ys, b = xc * ys, c = xc + ys;
    float r[81];
#pragma unroll
    for (int j = 0; j < 81; ++j) r[j] = 0.f;
    if (th >= 0.f) {
        r[0] = a;          r[1] = 1.f - a;
        r[10] = xc - b;    r[11] = b;        r[13] = 1.f - c + b; r[14] = ys - b;
        r[20] = a;         r[23] = 1.f - a;
        r[27] = b;         r[28] = ys - b;   r[30] = xc - b;      r[31] = 1.f - c + b;
        r[40] = 1.f;
        r[49] = 1.f - c + b; r[50] = xc - b; r[52] = ys - b;      r[53] = b;
        r[57] = 1.f - a;   r[60] = a;
        r[66] = ys - b;    r[67] = 1.f - c + b; r[69] = b;        r[70] = xc - b;
        r[79] = 1.f - a;   r[80] = a;
    } else {
        r[0] = c;          r[3] = 1.f - c;
        r[9] = -b;         r[10] = xc + b;   r[12] = b - ys;      r[13] = 1.f - a - b;
        r[19] = 1.f - c;   r[20] = c;
        r[30] = xc + b;    r[31] = 1.f - a - b; r[33] = -b;       r[34] = b - ys;
        r[40] = 1.f;
        r[46] = b - ys;    r[47] = -b;       r[49] = 1.f - a - b; r[50] = xc + b;
        r[60] = c;         r[61] = 1.f - c;
        r[67] = 1.f - a - b; r[68] = b - ys; r[70] = xc + b;      r[71] = -b;
        r[77] = 1.f - c;   r[80] = c;
    }
#pragma unroll
    for (int j = 0; j < 81; ++j) rm[i * 81 + j] = r[j] * al;
}

// ---------------------------------------------------------------------------
// Kernel 2: rw[b][cout][p*256 + cin] (bf16, p-major K layout)
// ---------------------------------------------------------------------------
__global__ __launch_bounds__(256)
void build_rw_kernel(const float* __restrict__ weight,
                     const float* __restrict__ rm,
                     ushort_t* __restrict__ rw) {
    __shared__ float rms[N_ * 81];        // 324 floats
    int tid = threadIdx.x;
    int b = blockIdx.y;
    for (int j = tid; j < N_ * 81; j += 256)
        rms[j] = rm[b * N_ * 81 + j];
    __syncthreads();

    int idx = blockIdx.x * 256 + tid;     // cout*256 + cin
    int cout = idx >> 8, cin = idx & 255;

    float wv[N_][9];
#pragma unroll
    for (int n = 0; n < N_; ++n)
#pragma unroll
        for (int q = 0; q < 9; ++q)
            wv[n][q] = weight[(size_t)(n * (COUT * CIN) + idx) * 9 + q];

    ushort_t* dst = rw + (size_t)(b * COUT + cout) * K_TOT + cin;
#pragma unroll
    for (int p = 0; p < 9; ++p) {
        float s = 0.f;
#pragma unroll
        for (int n = 0; n < N_; ++n)
#pragma unroll
            for (int q = 0; q < 9; ++q)
                s += rms[n * 81 + p * 9 + q] * wv[n][q];
        dst[p * 256] = f2bf(s);
    }
}

// ---------------------------------------------------------------------------
// Kernel 2a: zero the halo ring of each padded plane (260 px x 64 cin).
// grid: 64 planes (b*4 + cb4).
// ---------------------------------------------------------------------------
__global__ __launch_bounds__(256)
void halo_zero_kernel(ushort_t* __restrict__ xt) {
    ushort_t* base = xt + (size_t)blockIdx.x * PLANE * 64;
    int t = threadIdx.x;
    for (int i = t; i < 260; i += 256) {
        int py, px;
        if (i < 66)       { py = 0;  px = i; }
        else if (i < 132) { py = 65; px = i - 66; }
        else if (i < 196) { py = i - 132 + 1; px = 0; }
        else              { py = i - 196 + 1; px = 65; }
        ushort_t* d = base + (size_t)(py * PAD + px) * 64;
        int4 z = {0, 0, 0, 0};
#pragma unroll
        for (int q = 0; q < 8; ++q) *(int4*)(d + q * 8) = z;
    }
}

// ---------------------------------------------------------------------------
// Kernel 2b: interior repack: x fp32 [b][c][64][64] -> xt bf16
//   [b][cb4(4)][y+1][x+1][64cin].  grid (64 rows, 8 cb32, B_), 256 thr.
// ---------------------------------------------------------------------------
__global__ __launch_bounds__(256)
void nhwc_kernel(const float* __restrict__ x, ushort_t* __restrict__ xt) {
    int y    = blockIdx.x;
    int cb32 = blockIdx.y;
    int b    = blockIdx.z;
    __shared__ ushort_t tileT[64][40];    // [px][ci(32)], 80B rows
    int t = threadIdx.x;

    int ci = t & 31, seg = t >> 5;        // 8 segs x 8 px
    const float* src = x + ((size_t)(b * CIN + cb32 * 32 + ci) * HW + y * 64 + seg * 8);
    float4 f0 = ((const float4*)src)[0];
    float4 f1 = ((const float4*)src)[1];
#pragma unroll
    for (int q = 0; q < 4; ++q) tileT[seg * 8 + q][ci]     = f2bf(((float*)&f0)[q]);
#pragma unroll
    for (int q = 0; q < 4; ++q) tileT[seg * 8 + 4 + q][ci] = f2bf(((float*)&f1)[q]);
    __syncthreads();

    int px = t >> 2, cseg = t & 3;        // 64 px x 4 x 16B
    ushort_t* dst = xt + ((size_t)(b * 4 + (cb32 >> 1)) * PLANE + (y + 1) * PAD + px + 1) * 64
                       + (cb32 & 1) * 32 + cseg * 8;
    *(int4*)dst = *(const int4*)&tileT[px][cseg * 8];
}

// ---------------------------------------------------------------------------
// Kernel 3: 256(M) x 128(N) implicit-GEMM conv, BK=64, RING-3 LDS pipeline
// with counted vmcnt(6) (T3+T4 proper), R8's conflict-free swizzle s^(r&7)
// (T2), setprio (T5), bijective XCD swizzle (T1).
// 512 thr = 8 waves (2M x 4N), wave tile 128x32, acc[8][2].
// Per K-tile: 2 phases x 16 MFMA; ALL 6 loads of tile kt+2 issue in ph1;
// vmcnt(6) at tile end keeps kt+2 in flight, guarantees kt+1 landed.
// LDS: A 3x32KB + B 3x16KB = 144 KB.
// ---------------------------------------------------------------------------
__global__ __launch_bounds__(512, 1)
void conv_kernel(const ushort_t* __restrict__ xt,
                 const ushort_t* __restrict__ rw,
                 float* __restrict__ out) {
    int bid0 = blockIdx.x;
    int bid = (bid0 & 7) * 64 + (bid0 >> 3);   // 512 = 8*64: bijective
    int b    = bid >> 5;
    int tile = bid & 31;        // pixel tile: 2 image rows (128 px)
    int y0 = tile * 2;
    int tid = threadIdx.x;
    int lane = tid & 63, wid = tid >> 6;
    int wm = wid >> 2, wn = wid & 3;
    int rA = lane & 15, kseg = lane >> 4;

    __shared__ __align__(16) ushort_t As[3][256][64];   // 96 KB
    __shared__ __align__(16) ushort_t Bs[3][128][64];   // 48 KB
    ushort_t* AsB = &As[0][0][0];
    ushort_t* BsB = &Bs[0][0][0];

    f32x4 acc[8][2] = {};

    const ushort_t* rwb  = rw + (size_t)b * COUT * K_TOT;
    const ushort_t* xtb2 = xt + (size_t)b * 4 * PLANE * 64 + (size_t)y0 * PAD * 64;

    // ---- staging geometry ----
    // A: 2048 units of 16B; thread does units u = (wid*4+i)*64 + lane, i=0..3
    //    r = u>>3 = wid*32 + i*8 + (lane>>3);  slot = lane&7
    // B: 1024 units; u = (wid*2+i)*64 + lane, i=0..1; r = wid*16+i*8+(lane>>3)
    // source chunk = slot ^ (r&7) = (lane&7) ^ (lane>>3)   [involution]
    const int chnk = ((lane & 7) ^ (lane >> 3)) * 8;    // source seg (elems)
    const int arr  = (lane >> 3);                       // row sub-index
    // A row bases and source offsets (element units; add ako per tile)
    int asrc[4], adst[4];
#pragma unroll
    for (int i = 0; i < 4; ++i) {
        int r = wid * 32 + i * 8 + arr;
        asrc[i] = r * K_TOT + chnk;
        adst[i] = ((wid * 4 + i) * 64 + lane) * 8;
    }
    int bsrc[2], bdst[2];
#pragma unroll
    for (int i = 0; i < 2; ++i) {
        int r = wid * 16 + i * 8 + arr;                 // 0..127
        bsrc[i] = ((r >> 6) * PAD + (r & 63)) * 64 + chnk;
        bdst[i] = ((wid * 2 + i) * 64 + lane) * 8;
    }
    // read-side swizzled column base (elements): ((kh*4+kseg)^(rA&7))*8
    const int c0 = ((0 + kseg) ^ (rA & 7)) * 8;         // kh=0
    const int c1 = ((4 + kseg) ^ (rA & 7)) * 8;         // kh=1

#define STAGE(KTN, QS)                                                         \
    {                                                                          \
        int p_ = (KTN) / 4, c4_ = (KTN) & 3;                                   \
        int ako = p_ * 256 + c4_ * 64;                                         \
        int ph_ = p_ / 3, pw_ = p_ - 3 * ph_;                                  \
        ushort_t* da = AsB + (QS) * 16384;                                     \
        _Pragma("unroll")                                                      \
        for (int i = 0; i < 4; ++i)                                            \
            gl_lds16(rwb + asrc[i] + ako, da + adst[i]);                       \
        const ushort_t* sb = xtb2 + (size_t)(c4_ * PLANE + ph_ * PAD + pw_) * 64; \
        ushort_t* db = BsB + (QS) * 8192;                                      \
        _Pragma("unroll")                                                      \
        for (int i = 0; i < 2; ++i)                                            \
            gl_lds16(sb + bsrc[i], db + bdst[i]);                              \
    }

#define READ_AF(Q, MH2)                                                        \
    _Pragma("unroll")                                                          \
    for (int mi = 0; mi < 4; ++mi) {                                           \
        int row = wm * 128 + (MH2) * 64 + mi * 16 + rA;                        \
        af[mi][0] = *(const short8*)(AsB + (Q) * 16384 + row * 64 + c0);       \
        af[mi][1] = *(const short8*)(AsB + (Q) * 16384 + row * 64 + c1);       \
    }

#define READ_BF(Q)                                                             \
    _Pragma("unroll")                                                          \
    for (int ni = 0; ni < 2; ++ni) {                                           \
        int row = wn * 32 + ni * 16 + rA;                                      \
        bf[ni][0] = *(const short8*)(BsB + (Q) * 8192 + row * 64 + c0);        \
        bf[ni][1] = *(const short8*)(BsB + (Q) * 8192 + row * 64 + c1);        \
    }

#define DO_MFMA(MH2)                                                           \
    __builtin_amdgcn_s_setprio(1);                                             \
    _Pragma("unroll")                                                          \
    for (int mi = 0; mi < 4; ++mi)                                             \
        _Pragma("unroll")                                                      \
        for (int ni = 0; ni < 2; ++ni)                                         \
            _Pragma("unroll")                                                  \
            for (int kh = 0; kh < 2; ++kh)                                     \
                acc[(MH2) * 4 + mi][ni] = __builtin_amdgcn_mfma_f32_16x16x32_bf16( \
                    af[mi][kh], bf[ni][kh], acc[(MH2) * 4 + mi][ni], 0, 0, 0); \
    __builtin_amdgcn_s_setprio(0);

    // ---- prologue: stage tiles 0,1 into buffers 0,1 ----
    STAGE(0, 0);
    STAGE(1, 1);
    VMCNTN(6);               // tile 0 landed (tile 1's 6 still in flight)
    BARRIER();

    short8 af[4][2], bf[2][2];
    int qc = 0;              // buffer of tile kt
    for (int kt = 0; kt < NKT; ++kt) {
        int qs = (qc == 0) ? 2 : qc - 1;   // (qc+2)%3 : buffer of kt+2
        // ---- phase 1: m-half 0; stage ALL of tile kt+2 ----
        READ_AF(qc, 0);
        READ_BF(qc);
        if (kt + 2 < NKT) STAGE(kt + 2, qs);
        BARRIER();
        DO_MFMA(0);
        BARRIER();
        // ---- phase 2: m-half 1 (bf reused) ----
        READ_AF(qc, 1);
        BARRIER();
        DO_MFMA(1);
        // counted drain: tile kt+1 landed, tile kt+2 stays in flight
        if (kt < NKT - 2)       { VMCNTN(6); }
        else if (kt == NKT - 2) { VMCNTN(0); }
        BARRIER();
        qc = (qc == 2) ? 0 : qc + 1;
    }
#undef STAGE
#undef READ_AF
#undef READ_BF
#undef DO_MFMA

    // ---- epilogue: D[row=(lane>>4)*4+rr][col=lane&15] ----
    int row0 = (lane >> 4) * 4;
    int col  = lane & 15;
    float* outb = out + (size_t)b * COUT * HW + tile * 128;
#pragma unroll
    for (int am = 0; am < 8; ++am)
#pragma unroll
        for (int an = 0; an < 2; ++an)
#pragma unroll
            for (int rr = 0; rr < 4; ++rr) {
                int m = wm * 128 + am * 16 + row0 + rr;
                int n = wn * 32 + an * 16 + col;
                outb[(size_t)m * HW + n] = acc[am][an][rr];
            }
}

// ---------------------------------------------------------------------------
extern "C" void kernel_launch(void* const* d_in, const int* in_sizes, int n_in,
                              void* d_out, int out_size, void* d_ws, size_t ws_size,
                              hipStream_t stream) {
    const float* x      = (const float*)d_in[0];
    const float* alphas = (const float*)d_in[1];
    const float* angles = (const float*)d_in[2];
    const float* weight = (const float*)d_in[3];
    float* out = (float*)d_out;

    // ws: rw 18.87 MB | xt 35.68 MB | rm 20.7 KB
    ushort_t* rw = (ushort_t*)d_ws;
    ushort_t* xt = (ushort_t*)((char*)d_ws + (size_t)B_ * COUT * K_TOT * 2);
    float*    rm = (float*)((char*)d_ws + (size_t)B_ * COUT * K_TOT * 2
                                        + (size_t)64 * PLANE * 64 * 2);

    rot_mats_kernel<<<1, 64, 0, stream>>>(alphas, angles, rm);
    build_rw_kernel<<<dim3(COUT * CIN / 256, B_), 256, 0, stream>>>(weight, rm, rw);
    halo_zero_kernel<<<64, 256, 0, stream>>>(xt);
    nhwc_kernel<<<dim3(64, 8, B_), 256, 0, stream>>>(x, xt);
    conv_kernel<<<512, 512, 0, stream>>>(xt, rw, out);
}